// Round 1
// baseline (310.883 us; speedup 1.0000x reference)
//
#include <hip/hip_runtime.h>

// ---------------------------------------------------------------------------
// MMoE forward, MI355X/gfx950.
// Pipeline: [transpose weights -> bf16 [E][N][Kpad]] once, then per batch-chunk:
//   gather (emb -> bf16 expert_in, fp32 softmax gates)
//   grouped GEMM1 650->512 (bf16 MFMA, relu)  -> h1 bf16
//   grouped GEMM2 512->256 (relu)             -> h2 bf16
//   grouped GEMM3 256->128                    -> expert_out f32 (aliases h1)
//   combine (gates x experts) + task towers (fp32) -> out
// GEMM: 128x128 tile, BK=64, 4 waves, global_load_lds(16B) staging,
// double-buffered LDS, 2-phase schedule, XOR-swizzled LDS (swizzle applied on
// the global source AND the ds_read, LDS dest linear — guide rule #21).
// ---------------------------------------------------------------------------

typedef unsigned short u16;
typedef unsigned int u32;
typedef __attribute__((ext_vector_type(8))) __bf16 bf16x8;
typedef __attribute__((ext_vector_type(4))) float f32x4;

#define DEVINL __device__ __forceinline__

DEVINL u16 f2bf(float f) {            // float -> bf16 bits, round-nearest-even
  union { float f; u32 u; } x; x.f = f;
  u32 u = x.u;
  return (u16)((u + 0x7fffu + ((u >> 16) & 1u)) >> 16);
}
DEVINL float bf2f(u16 h) {
  union { u32 u; float f; } x; x.u = ((u32)h) << 16;
  return x.f;
}
DEVINL void gload16(const u16* g, u16* l) {   // 16B global -> LDS direct
  __builtin_amdgcn_global_load_lds((const __attribute__((address_space(1))) void*)g,
                                   (__attribute__((address_space(3))) void*)l,
                                   16, 0, 0);
}

// --------------------------- weight transpose ------------------------------
// W [E][K][N] f32 -> WT [E][N][Kpad] bf16, zero-padding K..Kpad.
// grid (Kpad/16, N/64, E), block 256.
__global__ __launch_bounds__(256)
void transpose_w_kernel(const float* __restrict__ W, u16* __restrict__ WT,
                        int K, int N, int Kpad)
{
  __shared__ float tbuf[16][65];   // +1 pad: kills 16-way bank conflict on read
  const int e = blockIdx.z;
  const float* We = W + (size_t)e * K * N;
  u16* Wt = WT + (size_t)e * N * Kpad;
  const int k0 = blockIdx.x * 16, n0 = blockIdx.y * 64;
#pragma unroll
  for (int p = 0; p < 4; ++p) {
    const int idx = threadIdx.x + p * 256;
    const int nl = idx & 63, kl = idx >> 6;
    const int gk = k0 + kl;
    tbuf[kl][nl] = (gk < K) ? We[(size_t)gk * N + n0 + nl] : 0.f;
  }
  __syncthreads();
#pragma unroll
  for (int p = 0; p < 4; ++p) {
    const int idx = threadIdx.x + p * 256;
    const int kl = idx & 15, nl = idx >> 4;
    Wt[(size_t)(n0 + nl) * Kpad + k0 + kl] = f2bf(tbuf[kl][nl]);
  }
}

// ------------------------------- gather ------------------------------------
// One wave per row: bf16 expert_in[row][704] (= deep 640 | cont 10 | pad 54),
// plus fp32 softmax gates[row][2][8] computed from lin_emb + cont.
__global__ __launch_bounds__(256)
void gather_kernel(const int* __restrict__ Xd, const float* __restrict__ Xc,
                   const float* __restrict__ lin_emb, const float* __restrict__ deep_emb,
                   const float* __restrict__ gW, const float* __restrict__ gb,
                   u16* __restrict__ ein, float* __restrict__ gates,
                   int rowBase, int Bc)
{
  __shared__ float gi[4][32];
  const int wid = threadIdx.x >> 6, lane = threadIdx.x & 63;
  const int rl = blockIdx.x * 4 + wid;           // row within chunk
  const int r = rowBase + rl;                    // global row
  const int* xd = Xd + (size_t)r * 20;
  u16* er = ein + (size_t)rl * 704;
#pragma unroll
  for (int i = 0; i < 10; ++i) {                 // 640 deep-emb elems, 10/lane
    const int j = i * 64 + lane;
    const int f = j >> 5, k = j & 31;
    const int idx = xd[f];                       // L1-broadcast
    er[j] = f2bf(deep_emb[((size_t)f * 100000 + idx) * 32 + k]);
  }
  if (lane < 10) er[640 + lane] = f2bf(Xc[(size_t)r * 10 + lane]);
  if (lane < 54) er[650 + lane] = 0;             // K padding -> zeros
  if (lane < 20) gi[wid][lane] = lin_emb[(size_t)lane * 100000 + xd[lane]];
  if (lane < 10) gi[wid][20 + lane] = Xc[(size_t)r * 10 + lane];
  asm volatile("s_waitcnt lgkmcnt(0)" ::: "memory");
  float logit = 0.f;
  const int t = lane >> 3, ee = lane & 7;
  if (lane < 16) {
    float a = gb[t * 8 + ee];
#pragma unroll
    for (int i = 0; i < 30; ++i) a += gi[wid][i] * gW[(t * 30 + i) * 8 + ee];
    logit = a;
  }
  float mx = logit;                              // softmax within 8-lane groups
#pragma unroll
  for (int d = 1; d < 8; d <<= 1) mx = fmaxf(mx, __shfl_xor(mx, d));
  float p = expf(logit - mx);
  float sm = p;
#pragma unroll
  for (int d = 1; d < 8; d <<= 1) sm += __shfl_xor(sm, d);
  if (lane < 16) gates[(size_t)rl * 16 + lane] = p / sm;
}

// ------------------------------ grouped GEMM -------------------------------
// C[e] = act(A[e] [M x K] * B[e]^T [N x K] + bias[e]);  K = Kpad (mult of 64),
// M,N mult of 128. A/B bf16 K-contiguous. grid (N/128, M/128, E), block 256.
template<bool RELU, typename CT>
__global__ __launch_bounds__(256, 2)
void gemm_kernel(const u16* __restrict__ A, size_t sAe,
                 const u16* __restrict__ Bw, size_t sBe,
                 CT* __restrict__ C, size_t sCe, int ldc,
                 const float* __restrict__ bias, int N, int K)
{
  __shared__ u16 As[2][8192];   // [128][64] bf16, XOR-swizzled, double-buffered
  __shared__ u16 Bs[2][8192];
  const int e = blockIdx.z;
  const u16* Ae = A + (size_t)e * sAe;
  const u16* Be = Bw + (size_t)e * sBe;
  const int row0 = blockIdx.y * 128;
  const int col0 = blockIdx.x * 128;
  const int tid = threadIdx.x;
  const int lane = tid & 63;
  const int wid = tid >> 6;
  const int wr = wid >> 1, wc = wid & 1;         // wave -> 64x64 quadrant

  // Staging: 16KB/tile = 16 wave-chunks of 1KB (64 lanes x 16B). LDS dest is
  // linear (wave-uniform base + lane*16); the swizzle is applied to the
  // GLOBAL source chunk index so that LDS (row, ch) holds global chunk
  // ch ^ (row&7)  -> ds_read applies the same XOR (involution).
  int rw_[4], gch_[4], ldsOff_[4];
#pragma unroll
  for (int i = 0; i < 4; ++i) {
    const int o = (wid * 4 + i) * 1024 + lane * 16;   // byte off in 16KB tile
    rw_[i] = o >> 7;                                  // row 0..127 (128B rows)
    const int ch = (o >> 4) & 7;                      // 16B chunk in row
    gch_[i] = ch ^ (rw_[i] & 7);                      // pre-swizzled source
    ldsOff_[i] = (wid * 4 + i) * 512;                 // u16 units, wave-uniform
  }
  const int KT = K >> 6;

  auto stage = [&](int buf, int kt) {
    const int kb = kt << 6;
#pragma unroll
    for (int i = 0; i < 4; ++i) {
      gload16(Ae + ((size_t)(row0 + rw_[i]) * K + kb + (gch_[i] << 3)),
              &As[buf][ldsOff_[i]]);
      gload16(Be + ((size_t)(col0 + rw_[i]) * K + kb + (gch_[i] << 3)),
              &Bs[buf][ldsOff_[i]]);
    }
  };

  f32x4 acc[4][4];
#pragma unroll
  for (int m = 0; m < 4; ++m)
#pragma unroll
    for (int n = 0; n < 4; ++n) acc[m][n] = {0.f, 0.f, 0.f, 0.f};

  stage(0, 0);
  __syncthreads();                               // drains vmcnt(0) too

  for (int kt = 0; kt < KT; ++kt) {
    const int cur = kt & 1;
    if (kt + 1 < KT) stage(cur ^ 1, kt + 1);     // prefetch in flight over MFMA
#pragma unroll
    for (int half = 0; half < 2; ++half) {       // k = 0..31, 32..63
      const int kp = half * 4 + (lane >> 4);     // 8-elem k-chunk index 0..7
      bf16x8 af[4], bfr[4];
#pragma unroll
      for (int m = 0; m < 4; ++m) {
        const int rw = wr * 64 + m * 16 + (lane & 15);
        af[m] = *(const bf16x8*)&As[cur][rw * 64 + ((kp ^ (rw & 7)) << 3)];
      }
#pragma unroll
      for (int n = 0; n < 4; ++n) {
        const int rw = wc * 64 + n * 16 + (lane & 15);
        bfr[n] = *(const bf16x8*)&Bs[cur][rw * 64 + ((kp ^ (rw & 7)) << 3)];
      }
#pragma unroll
      for (int m = 0; m < 4; ++m)
#pragma unroll
        for (int n = 0; n < 4; ++n)
          acc[m][n] = __builtin_amdgcn_mfma_f32_16x16x32_bf16(af[m], bfr[n],
                                                              acc[m][n], 0, 0, 0);
    }
    __syncthreads();   // next-tile staging complete + all reads of cur done
  }

  // epilogue: C/D layout col=lane&15, row=(lane>>4)*4+reg  [m91-verified]
  const int cl = lane & 15;
  const int rl4 = (lane >> 4) * 4;
#pragma unroll
  for (int n = 0; n < 4; ++n) {
    const int col = col0 + wc * 64 + n * 16 + cl;
    const float bv = bias[(size_t)e * N + col];
#pragma unroll
    for (int m = 0; m < 4; ++m) {
      const int grow = row0 + wr * 64 + m * 16 + rl4;
      CT* cp = C + (size_t)e * sCe + (size_t)grow * ldc + col;
#pragma unroll
      for (int j = 0; j < 4; ++j) {
        float v = acc[m][n][j] + bv;
        if (RELU) v = fmaxf(v, 0.f);
        if constexpr (sizeof(CT) == 2) cp[(size_t)j * ldc] = (CT)f2bf(v);
        else                           cp[(size_t)j * ldc] = (CT)v;
      }
    }
  }
}

// ------------------------- combine + task towers ---------------------------
// task_in[t] = sum_e gates[t][e] * expert_out[e]; towers 128->64(relu)->1.
// One wave per row, 4 rows/wave. W1 staged in LDS as bf16 (32KB).
__global__ __launch_bounds__(256)
void tower_kernel(const float* __restrict__ eo,    // [8][Bc][128] f32
                  const float* __restrict__ gates, // [Bc][2][8] f32
                  const float* __restrict__ tW1,   // [2][128][64] f32
                  const float* __restrict__ tb1,   // [2][64]
                  const float* __restrict__ tW2,   // [2][64]
                  const float* __restrict__ tb2,   // [2]
                  float* __restrict__ out,         // [B][2] f32
                  int rowBase, int Bc)
{
  __shared__ u16 w1s[2 * 128 * 64];
  __shared__ float tin[4][2][128];
  for (int i = threadIdx.x; i < 2 * 128 * 64; i += 256) w1s[i] = f2bf(tW1[i]);
  __syncthreads();
  const int wid = threadIdx.x >> 6, lane = threadIdx.x & 63;
  const int stride = gridDim.x * 4;
  for (int it = 0; it < 4; ++it) {
    const int r = blockIdx.x * 4 + wid + it * stride;
    const float* gp = gates + (size_t)r * 16;
    float g[16];
#pragma unroll
    for (int i = 0; i < 16; ++i) g[i] = gp[i];   // same addr -> broadcast
    float t0a = 0.f, t0b = 0.f, t1a = 0.f, t1b = 0.f;
#pragma unroll
    for (int ee = 0; ee < 8; ++ee) {
      const float* ep = eo + ((size_t)ee * Bc + r) * 128;
      const float a = ep[lane], b = ep[64 + lane];
      t0a += g[ee] * a;      t0b += g[ee] * b;
      t1a += g[8 + ee] * a;  t1b += g[8 + ee] * b;
    }
    tin[wid][0][lane] = t0a; tin[wid][0][64 + lane] = t0b;
    tin[wid][1][lane] = t1a; tin[wid][1][64 + lane] = t1b;
    asm volatile("s_waitcnt lgkmcnt(0)" ::: "memory");  // wave-local LDS ready
#pragma unroll
    for (int t = 0; t < 2; ++t) {
      float acc = tb1[t * 64 + lane];                   // lane = hidden unit h
#pragma unroll 8
      for (int d = 0; d < 128; ++d)
        acc += tin[wid][t][d] * bf2f(w1s[(t * 128 + d) * 64 + lane]);
      acc = fmaxf(acc, 0.f);
      float s = acc * tW2[t * 64 + lane];
#pragma unroll
      for (int dd = 1; dd < 64; dd <<= 1) s += __shfl_xor(s, dd);
      if (lane == 0) out[(size_t)(rowBase + r) * 2 + t] = s + tb2[t];
    }
    asm volatile("s_waitcnt lgkmcnt(0)" ::: "memory");  // reads done pre-overwrite
  }
}

// ------------------------------ launch -------------------------------------
extern "C" void kernel_launch(void* const* d_in, const int* in_sizes, int n_in,
                              void* d_out, int out_size, void* d_ws, size_t ws_size,
                              hipStream_t stream) {
  const int*   X_dis   = (const int*)  d_in[0];
  const float* X_cont  = (const float*)d_in[1];
  const float* lin_emb = (const float*)d_in[2];
  const float* deep_emb= (const float*)d_in[3];
  const float* eW1     = (const float*)d_in[4];
  const float* eb1     = (const float*)d_in[5];
  const float* eW2     = (const float*)d_in[6];
  const float* eb2     = (const float*)d_in[7];
  const float* eW3     = (const float*)d_in[8];
  const float* eb3     = (const float*)d_in[9];
  const float* gW      = (const float*)d_in[10];
  const float* gb      = (const float*)d_in[11];
  const float* tW1     = (const float*)d_in[12];
  const float* tb1     = (const float*)d_in[13];
  const float* tW2     = (const float*)d_in[14];
  const float* tb2     = (const float*)d_in[15];
  float* out = (float*)d_out;

  char* ws = (char*)d_ws;
  // persistent: transposed bf16 weights (8 MB total)
  u16* w1t = (u16*)(ws + 0);          // 8 x 512 x 704 x 2B = 5,767,168
  u16* w2t = (u16*)(ws + 5767168);    // 8 x 256 x 512 x 2B = 2,097,152
  u16* w3t = (u16*)(ws + 7864320);    // 8 x 128 x 256 x 2B =   524,288
  const size_t base = 8388608;

  const int B = 16384;
  // pick smallest chunk count whose footprint fits ws_size
  // per-chunk bytes/row: ein 1408 + gates 64 + h1 8192 + h2 4096 = 13760
  int NC = 1;
  while (NC < 128 && base + (size_t)(B / NC) * 13760ull > ws_size) NC <<= 1;
  const int Bc = B / NC;

  u16*   ein   = (u16*)  (ws + base);
  float* gates = (float*)(ws + base + (size_t)Bc * 1408);
  u16*   h1    = (u16*)  (ws + base + (size_t)Bc * 1472);
  u16*   h2    = (u16*)  (ws + base + (size_t)Bc * 1472 + (size_t)Bc * 8192);
  float* eo    = (float*)h1;          // aliases h1 (dead after GEMM2); 4096B/row <= 8192B/row

  transpose_w_kernel<<<dim3(44, 8, 8), 256, 0, stream>>>(eW1, w1t, 650, 512, 704);
  transpose_w_kernel<<<dim3(32, 4, 8), 256, 0, stream>>>(eW2, w2t, 512, 256, 512);
  transpose_w_kernel<<<dim3(16, 2, 8), 256, 0, stream>>>(eW3, w3t, 256, 128, 256);

  for (int c = 0; c < NC; ++c) {
    const int rowBase = c * Bc;
    gather_kernel<<<Bc / 4, 256, 0, stream>>>(X_dis, X_cont, lin_emb, deep_emb,
                                              gW, gb, ein, gates, rowBase, Bc);
    gemm_kernel<true,  u16><<<dim3(4, Bc / 128, 8), 256, 0, stream>>>(
        ein, 0,                 w1t, (size_t)512 * 704,
        h1, (size_t)Bc * 512, 512, eb1, 512, 704);
    gemm_kernel<true,  u16><<<dim3(2, Bc / 128, 8), 256, 0, stream>>>(
        h1, (size_t)Bc * 512,   w2t, (size_t)256 * 512,
        h2, (size_t)Bc * 256, 256, eb2, 256, 512);
    gemm_kernel<false, float><<<dim3(1, Bc / 128, 8), 256, 0, stream>>>(
        h2, (size_t)Bc * 256,   w3t, (size_t)128 * 256,
        eo, (size_t)Bc * 128, 128, eb3, 128, 256);
    tower_kernel<<<Bc / 16, 256, 0, stream>>>(eo, gates, tW1, tb1, tW2, tb2,
                                              out, rowBase, Bc);
  }
}